// Round 8
// baseline (240.858 us; speedup 1.0000x reference)
//
// ROUND 8: fully-fused single-pass pipeline. Key algebra: per-token q-max and
// global k-max cancel exactly in num/den (eps perturbation ~2e-4 relative) ->
// drop them. phi_k + kvs computed inside k_qkv (LDS stage + MFMA + atomicAdd);
// sk/vt buffers, k_kvs and k_finmax eliminated.
#include <hip/hip_runtime.h>
#include <cstdint>

typedef __attribute__((ext_vector_type(4))) float f32x4;
typedef __attribute__((ext_vector_type(8))) short short8;
typedef __attribute__((ext_vector_type(4))) unsigned short us4;
typedef __attribute__((ext_vector_type(8))) unsigned short us8;

#define DEV __device__ __forceinline__

DEV unsigned short f2b(float f) {
  unsigned u = __builtin_bit_cast(unsigned, f);
  return (unsigned short)((u + 0x7fffu + ((u >> 16) & 1u)) >> 16);
}
DEV float b2f(unsigned short h) {
  unsigned u = ((unsigned)h) << 16;
  return __builtin_bit_cast(float, u);
}

constexpr float SQ_SCALE = 0.35355339059327379f;    // 64^-0.25 (tau=1)
constexpr float RATIO    = 0.18257418583505536f;    // 1/sqrt(30)
constexpr float REPS     = 0.18257418583505536e-6f; // RATIO * 1e-6

// B=16, T=4096, N=65536, C_IN=128, H=8, D=64, M=30 (pad 32)
// wqkv columns, per head h (256 cols each): [0,64) q | [64,128) k |
//   [128,192) v | [192,224) ddq (folded proj@Wq) | [224,256) ddk
constexpr size_t OF_WQKV = 0;         // 2048*128 bf16 = 524288
constexpr size_t OF_WBP  = 524288;    // 2048 f32 = 8192
constexpr size_t OF_PHIQ = 532480;    // 65536*8*32 bf16 = 33554432
constexpr size_t OF_KVS  = 34086912;  // 128*32*64 f32 = 1048576
constexpr size_t OF_KSUM = 35135488;  // 128*32 f32 = 16384
constexpr size_t OF_GT   = 35151872;  // 128*64*32 bf16 = 524288
constexpr size_t WS_NEED = 35676160;

// ---------------- K0: pack weights (per-h col order) + fold proj ----------------
__global__ __launch_bounds__(256) void k_pack(
    const float* __restrict__ wq, const float* __restrict__ wk,
    const float* __restrict__ wv, const float* __restrict__ bq,
    const float* __restrict__ bk, const float* __restrict__ bv,
    const float* __restrict__ proj,
    unsigned short* __restrict__ wqkv, float* __restrict__ wbp) {
  int bid = blockIdx.x, tid = threadIdx.x;
  if (bid < 768) {
    int id = bid * 256 + tid;            // (c,k), c < 1536
    int k = id & 127, c = id >> 7;
    int h = c / 192, rem = c % 192, mat = rem >> 6, d = rem & 63;
    const float* w = (mat == 0) ? wq : ((mat == 1) ? wk : wv);
    float s = (mat < 2) ? SQ_SCALE : 1.0f;
    int col = h * 256 + mat * 64 + d;
    wqkv[col * 128 + k] = f2b(w[(h * 64 + d) * 128 + k] * s);
  } else if (bid < 784) {
    // fold: P_h[m][k] = sum_d proj[m][d] * W_scaled[h*64+d][k]
    __shared__ float wsm[64 * 128];
    __shared__ float ps[32 * 64];
    __shared__ float bs[64];
    int db = bid - 768, mat2 = db >> 3, h = db & 7;
    const float* wsrc = (mat2 == 0) ? wq : wk;
    const float* bsrc = (mat2 == 0) ? bq : bk;
    for (int i = tid; i < 8192; i += 256) wsm[i] = wsrc[h * 8192 + i] * SQ_SCALE;
    for (int i = tid; i < 2048; i += 256) {
      int m = i >> 6, d = i & 63;
      ps[i] = (m < 30) ? proj[m * 64 + d] : 0.0f;
    }
    if (tid < 64) bs[tid] = bsrc[h * 64 + tid] * SQ_SCALE;
    __syncthreads();
    int m = tid >> 3, kseg = tid & 7;
    int col = h * 256 + 192 + mat2 * 32 + m;
#pragma unroll 4
    for (int kk = 0; kk < 16; ++kk) {
      int k = kseg * 16 + kk;
      float a = 0.f;
      for (int d = 0; d < 64; ++d) a += ps[m * 64 + d] * wsm[d * 128 + k];
      wqkv[col * 128 + k] = f2b(a);
    }
    if (tid < 32) {
      float a = 0.f;
      for (int d = 0; d < 64; ++d) a += ps[tid * 64 + d] * bs[d];
      wbp[h * 256 + 192 + mat2 * 32 + tid] = a;
    }
  } else {
    for (int i = tid; i < 1536; i += 256) {
      int h = i / 192, rem = i % 192, mat = rem >> 6, d = rem & 63;
      const float* bb = (mat == 0) ? bq : ((mat == 1) ? bk : bv);
      wbp[h * 256 + mat * 64 + d] = bb[h * 64 + d] * ((mat < 2) ? SQ_SCALE : 1.0f);
    }
  }
}

// ---------------- K1: fused GEMM + phi + kvs/ksum accumulation ----------------
__global__ __launch_bounds__(256) void k_qkv(
    const float* __restrict__ x, const unsigned short* __restrict__ wqkv,
    const float* __restrict__ wbp, unsigned short* __restrict__ phiq,
    float* __restrict__ kvs, float* __restrict__ ksum) {
  __shared__ unsigned short xs[64 * 128];   // 16KB swizzled bf16 x-tile
  __shared__ unsigned short vts[64 * 64];   // 8KB [d][t] bf16 swizzled
  __shared__ unsigned short phit[32 * 64];  // 4KB [m][t] bf16 swizzled
  __shared__ unsigned short phiqs[64 * 32]; // 4KB [tok][m] bf16
  __shared__ float diagq[64];
  __shared__ float diagk[64];

  int tid = threadIdx.x;
  int w = tid >> 6, l = tid & 63;
  int g = l >> 4, li = l & 15;
  int n0 = blockIdx.x * 64;
  int b = n0 >> 12;

  // stage x tile -> bf16 LDS (swizzled)
  {
    int row = tid >> 2, seg = tid & 3;
    const float* src = x + (size_t)(n0 + row) * 128 + seg * 32;
#pragma unroll
    for (int q8 = 0; q8 < 4; ++q8) {
      f32x4 a = *reinterpret_cast<const f32x4*>(src + q8 * 8);
      f32x4 c = *reinterpret_cast<const f32x4*>(src + q8 * 8 + 4);
      us8 o;
      o[0] = f2b(a[0]); o[1] = f2b(a[1]); o[2] = f2b(a[2]); o[3] = f2b(a[3]);
      o[4] = f2b(c[0]); o[5] = f2b(c[1]); o[6] = f2b(c[2]); o[7] = f2b(c[3]);
      int byte = (row * 256 + seg * 64 + q8 * 16) ^ ((row & 7) << 4);
      *reinterpret_cast<us8*>(((char*)xs) + byte) = o;
    }
  }
  __syncthreads();

  const short* wq_s = reinterpret_cast<const short*>(wqkv);

  for (int h = 0; h < 8; ++h) {
    int bh = b * 8 + h;
    int bcol = h * 256 + w * 64;   // wave roles: w0=q, w1=k, w2=v, w3=ddq|ddk

    f32x4 acc[4][4] = {};
#pragma unroll
    for (int ks = 0; ks < 4; ++ks) {
      short8 a[4], bb[4];
#pragma unroll
      for (int fi = 0; fi < 4; ++fi) {
        int tokl = fi * 16 + li;
        int byte = (tokl * 256 + (ks * 32 + g * 8) * 2) ^ ((tokl & 7) << 4);
        a[fi] = *reinterpret_cast<const short8*>(((const char*)xs) + byte);
      }
#pragma unroll
      for (int fj = 0; fj < 4; ++fj)
        bb[fj] = *reinterpret_cast<const short8*>(wq_s + (bcol + fj * 16 + li) * 128 + ks * 32 + g * 8);
#pragma unroll
      for (int fi = 0; fi < 4; ++fi)
#pragma unroll
        for (int fj = 0; fj < 4; ++fj)
          acc[fi][fj] = __builtin_amdgcn_mfma_f32_16x16x32_bf16(a[fi], bb[fj], acc[fi][fj], 0, 0, 0);
    }
#pragma unroll
    for (int fj = 0; fj < 4; ++fj) {
      float bias = wbp[bcol + fj * 16 + li];
#pragma unroll
      for (int fi = 0; fi < 4; ++fi)
#pragma unroll
        for (int r = 0; r < 4; ++r) acc[fi][fj][r] += bias;
    }

    if (w < 2) {
      // q/k tile -> diag = 0.5*sum_d data^2 per token
      float t4[4][4];
#pragma unroll
      for (int fi = 0; fi < 4; ++fi)
#pragma unroll
        for (int r = 0; r < 4; ++r) {
          float s = 0.f;
#pragma unroll
          for (int fj = 0; fj < 4; ++fj) { float v = acc[fi][fj][r]; s += v * v; }
          t4[fi][r] = s;
        }
#pragma unroll
      for (int mask = 1; mask <= 8; mask <<= 1)
#pragma unroll
        for (int fi = 0; fi < 4; ++fi)
#pragma unroll
          for (int r = 0; r < 4; ++r)
            t4[fi][r] += __shfl_xor(t4[fi][r], mask, 64);
      if (li == 0) {
        float* dst = (w == 0) ? diagq : diagk;
#pragma unroll
        for (int fi = 0; fi < 4; ++fi)
#pragma unroll
          for (int r = 0; r < 4; ++r)
            dst[fi * 16 + g * 4 + r] = 0.5f * t4[fi][r];
      }
    } else if (w == 2) {
      // v tile -> vts[d][t] bf16 swizzled
#pragma unroll
      for (int fi = 0; fi < 4; ++fi)
#pragma unroll
        for (int fj = 0; fj < 4; ++fj) {
          int d = fj * 16 + li;
          us4 o;
          o[0] = f2b(acc[fi][fj][0]); o[1] = f2b(acc[fi][fj][1]);
          o[2] = f2b(acc[fi][fj][2]); o[3] = f2b(acc[fi][fj][3]);
          int byte = (d * 128 + (fi * 16 + g * 4) * 2) ^ ((d & 7) << 4);
          *reinterpret_cast<us4*>(((char*)vts) + byte) = o;
        }
    }
    __syncthreads();   // diag + vts ready

    if (w == 3) {
      // fj 0,1 = ddq -> phi_q (no per-token max; cancels in num/den)
      // fj 2,3 = ddk -> phi_k (no global max; cancels per (b,h))
      float ksp0 = 0.f, ksp1 = 0.f;
#pragma unroll
      for (int fj = 0; fj < 4; ++fj) {
        int m = (fj & 1) * 16 + li;
        bool valid = (m < 30);
        bool isq = (fj < 2);
#pragma unroll
        for (int fi = 0; fi < 4; ++fi)
#pragma unroll
          for (int r = 0; r < 4; ++r) {
            int tok = fi * 16 + g * 4 + r;
            float dgv = isq ? diagq[tok] : diagk[tok];
            float ph = valid ? (RATIO * __expf(acc[fi][fj][r] - dgv) + REPS) : 0.f;
            if (isq) {
              *reinterpret_cast<unsigned short*>(((char*)phiqs) + tok * 64 + m * 2) = f2b(ph);
            } else {
              int byte = (m * 128 + tok * 2) ^ ((m & 7) << 4);
              *reinterpret_cast<unsigned short*>(((char*)phit) + byte) = f2b(ph);
              if (fj == 2) ksp0 += ph; else ksp1 += ph;
            }
          }
      }
      // ksum: sum over tokens (reduce over g groups)
      ksp0 += __shfl_xor(ksp0, 16, 64); ksp0 += __shfl_xor(ksp0, 32, 64);
      ksp1 += __shfl_xor(ksp1, 16, 64); ksp1 += __shfl_xor(ksp1, 32, 64);
      if (g == 0) {
        atomicAdd(&ksum[bh * 32 + li], ksp0);
        atomicAdd(&ksum[bh * 32 + 16 + li], ksp1);
      }
    }
    __syncthreads();   // phit + phiqs ready

    // kvs partial: [32 m x 64 d] = phi_k^T @ v ; wave w owns d-cols 16w..16w+15
    f32x4 kacc[2] = {};
#pragma unroll
    for (int ks2 = 0; ks2 < 2; ++ks2) {
      int byteA0 = (li * 128 + (ks2 * 32 + g * 8) * 2) ^ ((li & 7) << 4);
      int byteA1 = ((16 + li) * 128 + (ks2 * 32 + g * 8) * 2) ^ ((li & 7) << 4);
      int dcol = w * 16 + li;
      int byteB = (dcol * 128 + (ks2 * 32 + g * 8) * 2) ^ ((dcol & 7) << 4);
      short8 a0 = *reinterpret_cast<const short8*>(((const char*)phit) + byteA0);
      short8 a1 = *reinterpret_cast<const short8*>(((const char*)phit) + byteA1);
      short8 bb = *reinterpret_cast<const short8*>(((const char*)vts) + byteB);
      kacc[0] = __builtin_amdgcn_mfma_f32_16x16x32_bf16(a0, bb, kacc[0], 0, 0, 0);
      kacc[1] = __builtin_amdgcn_mfma_f32_16x16x32_bf16(a1, bb, kacc[1], 0, 0, 0);
    }
#pragma unroll
    for (int fm = 0; fm < 2; ++fm)
#pragma unroll
      for (int r = 0; r < 4; ++r)
        atomicAdd(&kvs[(size_t)bh * 2048 + (fm * 16 + g * 4 + r) * 64 + w * 16 + li], kacc[fm][r]);

    // coalesced phi_q store: one us8 per thread
    {
      int tok = tid & 63;
      us8 o = *reinterpret_cast<const us8*>(((const char*)phiqs) + tok * 64 + w * 16);
      *reinterpret_cast<us8*>(&phiq[((size_t)(n0 + tok) * 8 + h) * 32 + w * 8]) = o;
    }
    __syncthreads();   // protect LDS reuse next h
  }
}

// ---------------- K2: fold Wo into kvs: Gt[bh][c][m] ----------------
__global__ __launch_bounds__(256) void k_fold(
    const float* __restrict__ kvs, const float* __restrict__ wo,
    unsigned short* __restrict__ Gt) {
  __shared__ float kv[32 * 64];
  __shared__ float wos[64 * 64];  // [d][c]
  int tid = threadIdx.x;
  int bh = blockIdx.x, h = bh & 7;
  for (int i = tid; i < 2048; i += 256) kv[i] = kvs[(size_t)bh * 2048 + i];
  {
    int c = tid >> 2, dseg = tid & 3;
#pragma unroll
    for (int jj = 0; jj < 16; ++jj) {
      int d = dseg * 16 + jj;
      wos[d * 64 + c] = wo[c * 512 + h * 64 + d];
    }
  }
  __syncthreads();
  int c = tid & 63, mseg = tid >> 6;
  us8 outv;
#pragma unroll
  for (int jj = 0; jj < 8; ++jj) {
    int m = mseg * 8 + jj;
    float a = 0.f;
    for (int d = 0; d < 64; ++d) a += kv[m * 64 + d] * wos[d * 64 + c];
    outv[jj] = f2b(a);
  }
  *reinterpret_cast<us8*>(Gt + ((size_t)bh * 64 + c) * 32 + mseg * 8) = outv;
}

// ---------------- K3: out = sum_h (phi_q @ G_h^T)/den_h + bias (f32 out) ----------------
__global__ __launch_bounds__(256) void k_out(
    const unsigned short* __restrict__ phiq, const unsigned short* __restrict__ Gt,
    const float* __restrict__ ksum, const float* __restrict__ wob,
    float* __restrict__ out) {
  int tid = threadIdx.x;
  int w = tid >> 6, l = tid & 63, g = l >> 4, li = l & 15;
  int n0 = blockIdx.x * 64 + w * 16;
  int b = (blockIdx.x * 64) >> 12;
  const short* phi_s = reinterpret_cast<const short*>(phiq);
  const short* gt_s = reinterpret_cast<const short*>(Gt);
  f32x4 oacc[4] = {};
#pragma unroll
  for (int h = 0; h < 8; ++h) {
    int bh = b * 8 + h;
    int tok = n0 + li;
    short8 a = *reinterpret_cast<const short8*>(phi_s + ((size_t)tok * 8 + h) * 32 + g * 8);
    const float* ksrow = ksum + bh * 32 + g * 8;
    float den = 0.f;
#pragma unroll
    for (int jj = 0; jj < 8; ++jj) den += b2f((unsigned short)a[jj]) * ksrow[jj];
    den += __shfl_xor(den, 16, 64);
    den += __shfl_xor(den, 32, 64);
    float rd = 1.0f / den;
    f32x4 nm[4];
#pragma unroll
    for (int fj = 0; fj < 4; ++fj) {
      short8 bb = *reinterpret_cast<const short8*>(gt_s + ((size_t)bh * 64 + fj * 16 + li) * 32 + g * 8);
      f32x4 z = {};
      nm[fj] = __builtin_amdgcn_mfma_f32_16x16x32_bf16(a, bb, z, 0, 0, 0);
    }
#pragma unroll
    for (int r = 0; r < 4; ++r) {
      float rdr = __shfl(rd, g * 4 + r, 64);
#pragma unroll
      for (int fj = 0; fj < 4; ++fj) oacc[fj][r] += nm[fj][r] * rdr;
    }
  }
#pragma unroll
  for (int fj = 0; fj < 4; ++fj) {
    float bias = wob[fj * 16 + li];
#pragma unroll
    for (int r = 0; r < 4; ++r) {
      int n = n0 + g * 4 + r;
      out[(size_t)n * 64 + fj * 16 + li] = oacc[fj][r] + bias;
    }
  }
}

extern "C" void kernel_launch(void* const* d_in, const int* in_sizes, int n_in,
                              void* d_out, int out_size, void* d_ws, size_t ws_size,
                              hipStream_t stream) {
  const int expect[10] = {8388608, 65536, 512, 65536, 512, 65536, 512, 32768, 64, 1920};
  if (n_in != 10) return;
  for (int i = 0; i < 10; ++i) if (in_sizes[i] != expect[i]) return;
  if (out_size != 4194304) return;
  if (ws_size < WS_NEED) return;

  const float* x    = (const float*)d_in[0];
  const float* wq   = (const float*)d_in[1];
  const float* bq   = (const float*)d_in[2];
  const float* wk   = (const float*)d_in[3];
  const float* bk   = (const float*)d_in[4];
  const float* wv   = (const float*)d_in[5];
  const float* bv   = (const float*)d_in[6];
  const float* wo   = (const float*)d_in[7];
  const float* wob  = (const float*)d_in[8];
  const float* proj = (const float*)d_in[9];

  char* ws = (char*)d_ws;
  unsigned short* wqkv = (unsigned short*)(ws + OF_WQKV);
  float*          wbp  = (float*)(ws + OF_WBP);
  unsigned short* phiq = (unsigned short*)(ws + OF_PHIQ);
  float*          kvs  = (float*)(ws + OF_KVS);
  float*          ksum = (float*)(ws + OF_KSUM);
  unsigned short* Gt   = (unsigned short*)(ws + OF_GT);

  // zero kvs + ksum (contiguous)
  (void)hipMemsetAsync(ws + OF_KVS, 0, 1048576 + 16384, stream);

  k_pack<<<785, 256, 0, stream>>>(wq, wk, wv, bq, bk, bv, proj, wqkv, wbp);
  k_qkv<<<1024, 256, 0, stream>>>(x, wqkv, wbp, phiq, kvs, ksum);
  k_fold<<<128, 256, 0, stream>>>(kvs, wo, Gt);
  k_out<<<1024, 256, 0, stream>>>(phiq, Gt, ksum, wob, (float*)d_out);
}

// Round 9
// 204.197 us; speedup vs baseline: 1.1795x; 1.1795x over previous
//
// ROUND 9: revert r8's over-fusion; keep the no-max algebra. r7 dataflow with
// coalesced head-major outputs (phiq/phik[h][n][32], v[h][n][64]) staged via
// per-wave LDS -> us8 stores. k_kvs re-stages into the r7-proven swizzled
// MFMA tiles. No maxkey/k_finmax; exp computed once in f32 in k_qkv.
#include <hip/hip_runtime.h>
#include <cstdint>

typedef __attribute__((ext_vector_type(4))) float f32x4;
typedef __attribute__((ext_vector_type(8))) short short8;
typedef __attribute__((ext_vector_type(8))) unsigned short us8;

#define DEV __device__ __forceinline__

DEV unsigned short f2b(float f) {
  unsigned u = __builtin_bit_cast(unsigned, f);
  return (unsigned short)((u + 0x7fffu + ((u >> 16) & 1u)) >> 16);
}
DEV float b2f(unsigned short h) {
  unsigned u = ((unsigned)h) << 16;
  return __builtin_bit_cast(float, u);
}

constexpr float SQ_SCALE = 0.35355339059327379f;    // 64^-0.25 (tau=1)
constexpr float RATIO    = 0.18257418583505536f;    // 1/sqrt(30)
constexpr float REPS     = 0.18257418583505536e-6f; // RATIO * 1e-6

// B=16, T=4096, N=65536, C_IN=128, H=8, D=64, M=30 (pad 32)
// wqkv cols: [0,512) q | [512,1024) k | [1024,1536) v | [1536,1792) ddq | [1792,2048) ddk
constexpr size_t OF_WQKV = 0;          // 2048*128 bf16 = 524288
constexpr size_t OF_WBP  = 524288;     // 2048 f32
constexpr size_t OF_PHIQ = 532480;     // [8][65536][32] bf16 = 33554432
constexpr size_t OF_PHIK = 34086912;   // [8][65536][32] bf16 = 33554432
constexpr size_t OF_V    = 67641344;   // [8][65536][64] bf16 = 67108864
constexpr size_t OF_KVS  = 134750208;  // 128*32*64 f32 = 1048576
constexpr size_t OF_KSUM = 135798784;  // 128*32 f32 = 16384
constexpr size_t OF_GT   = OF_PHIK;    // 128*64*32 bf16 (overlaps dead phik)
constexpr size_t WS_NEED = 135815168;

// ---------------- K0: pack weights + fold proj into Wq/Wk ----------------
__global__ __launch_bounds__(256) void k_pack(
    const float* __restrict__ wq, const float* __restrict__ wk,
    const float* __restrict__ wv, const float* __restrict__ bq,
    const float* __restrict__ bk, const float* __restrict__ bv,
    const float* __restrict__ proj,
    unsigned short* __restrict__ wqkv, float* __restrict__ wbp) {
  int bid = blockIdx.x, tid = threadIdx.x;
  if (bid < 768) {
    int id = bid * 256 + tid;
    int c = id >> 7, k = id & 127;
    int mat = c >> 9, row = c & 511;
    const float* w = (mat == 0) ? wq : ((mat == 1) ? wk : wv);
    float s = (mat < 2) ? SQ_SCALE : 1.0f;
    wqkv[id] = f2b(w[row * 128 + k] * s);
  } else if (bid < 784) {
    __shared__ float wsm[64 * 128];
    __shared__ float ps[32 * 64];
    __shared__ float bs[64];
    int db = bid - 768, mat2 = db >> 3, h = db & 7;
    const float* wsrc = (mat2 == 0) ? wq : wk;
    const float* bsrc = (mat2 == 0) ? bq : bk;
    for (int i = tid; i < 8192; i += 256) wsm[i] = wsrc[h * 8192 + i] * SQ_SCALE;
    for (int i = tid; i < 2048; i += 256) {
      int m = i >> 6, d = i & 63;
      ps[i] = (m < 30) ? proj[m * 64 + d] : 0.0f;
    }
    if (tid < 64) bs[tid] = bsrc[h * 64 + tid] * SQ_SCALE;
    __syncthreads();
    int m = tid >> 3, kseg = tid & 7;
    int col = 1536 + mat2 * 256 + h * 32 + m;
#pragma unroll 4
    for (int kk = 0; kk < 16; ++kk) {
      int k = kseg * 16 + kk;
      float a = 0.f;
      for (int d = 0; d < 64; ++d) a += ps[m * 64 + d] * wsm[d * 128 + k];
      wqkv[col * 128 + k] = f2b(a);
    }
    if (tid < 32) {
      float a = 0.f;
      for (int d = 0; d < 64; ++d) a += ps[tid * 64 + d] * bs[d];
      wbp[1536 + mat2 * 256 + h * 32 + tid] = a;
    }
  } else {
    for (int i = tid; i < 1536; i += 256) {
      int mat = i >> 9, row = i & 511;
      const float* bb = (mat == 0) ? bq : ((mat == 1) ? bk : bv);
      wbp[i] = bb[row] * ((mat < 2) ? SQ_SCALE : 1.0f);
    }
  }
}

// ---------------- K1: fused GEMM -> diag, v, phi_q, phi_k (all coalesced) ----------------
__global__ __launch_bounds__(256) void k_qkv(
    const float* __restrict__ x, const unsigned short* __restrict__ wqkv,
    const float* __restrict__ wbp,
    unsigned short* __restrict__ phiq, unsigned short* __restrict__ phik,
    unsigned short* __restrict__ vglob) {
  __shared__ unsigned short xs[64 * 128];       // 16KB swizzled bf16 x-tile
  __shared__ unsigned short scratch[4][4096];   // 8KB per-wave stage
  __shared__ float diag_s[2][512];              // [q|k][h*64 + tok]

  int tid = threadIdx.x;
  int w = tid >> 6, l = tid & 63;
  int g = l >> 4, li = l & 15;
  int n0 = blockIdx.x * 64;

  {
    int row = tid >> 2, seg = tid & 3;
    const float* src = x + (size_t)(n0 + row) * 128 + seg * 32;
#pragma unroll
    for (int q8 = 0; q8 < 4; ++q8) {
      f32x4 a = *reinterpret_cast<const f32x4*>(src + q8 * 8);
      f32x4 c = *reinterpret_cast<const f32x4*>(src + q8 * 8 + 4);
      us8 o;
      o[0] = f2b(a[0]); o[1] = f2b(a[1]); o[2] = f2b(a[2]); o[3] = f2b(a[3]);
      o[4] = f2b(c[0]); o[5] = f2b(c[1]); o[6] = f2b(c[2]); o[7] = f2b(c[3]);
      int byte = (row * 256 + seg * 64 + q8 * 16) ^ ((row & 7) << 4);
      *reinterpret_cast<us8*>(((char*)xs) + byte) = o;
    }
  }
  __syncthreads();

  const short* wq_s = reinterpret_cast<const short*>(wqkv);
  char* scr = (char*)scratch[w];

  for (int j = 0; j < 8; ++j) {
    if (j == 6) __syncthreads();   // diag_s complete before dd tiles
    int tl = j * 4 + w;
    int bcol = tl * 64;

    f32x4 acc[4][4] = {};
#pragma unroll
    for (int ks = 0; ks < 4; ++ks) {
      short8 a[4], bb[4];
#pragma unroll
      for (int fi = 0; fi < 4; ++fi) {
        int tokl = fi * 16 + li;
        int byte = (tokl * 256 + (ks * 32 + g * 8) * 2) ^ ((tokl & 7) << 4);
        a[fi] = *reinterpret_cast<const short8*>(((const char*)xs) + byte);
      }
#pragma unroll
      for (int fj = 0; fj < 4; ++fj)
        bb[fj] = *reinterpret_cast<const short8*>(wq_s + (bcol + fj * 16 + li) * 128 + ks * 32 + g * 8);
#pragma unroll
      for (int fi = 0; fi < 4; ++fi)
#pragma unroll
        for (int fj = 0; fj < 4; ++fj)
          acc[fi][fj] = __builtin_amdgcn_mfma_f32_16x16x32_bf16(a[fi], bb[fj], acc[fi][fj], 0, 0, 0);
    }
#pragma unroll
    for (int fj = 0; fj < 4; ++fj) {
      float bias = wbp[bcol + fj * 16 + li];
#pragma unroll
      for (int fi = 0; fi < 4; ++fi)
#pragma unroll
        for (int r = 0; r < 4; ++r) acc[fi][fj][r] += bias;
    }

    if (j < 4) {
      // q/k tile -> diag = 0.5*sum_d data^2 per token
      int qk = j >> 1;
      int h = tl - qk * 8;
      float t4[4][4];
#pragma unroll
      for (int fi = 0; fi < 4; ++fi)
#pragma unroll
        for (int r = 0; r < 4; ++r) {
          float s = 0.f;
#pragma unroll
          for (int fj = 0; fj < 4; ++fj) { float v = acc[fi][fj][r]; s += v * v; }
          t4[fi][r] = s;
        }
#pragma unroll
      for (int mask = 1; mask <= 8; mask <<= 1)
#pragma unroll
        for (int fi = 0; fi < 4; ++fi)
#pragma unroll
          for (int r = 0; r < 4; ++r)
            t4[fi][r] += __shfl_xor(t4[fi][r], mask, 64);
      if (li == 0) {
#pragma unroll
        for (int fi = 0; fi < 4; ++fi)
#pragma unroll
          for (int r = 0; r < 4; ++r)
            diag_s[qk][h * 64 + fi * 16 + g * 4 + r] = 0.5f * t4[fi][r];
      }
    } else if (j < 6) {
      // v tile: stage [tok][d] in per-wave LDS, then coalesced us8 stores
      int h = tl - 16;
#pragma unroll
      for (int fi = 0; fi < 4; ++fi)
#pragma unroll
        for (int fj = 0; fj < 4; ++fj) {
          int d = fj * 16 + li;
#pragma unroll
          for (int r = 0; r < 4; ++r) {
            int tok = fi * 16 + g * 4 + r;
            int byte = (tok * 128 + d * 2) ^ ((tok & 7) << 4);
            *reinterpret_cast<unsigned short*>(scr + byte) = f2b(acc[fi][fj][r]);
          }
        }
      // wave-local RAW through LDS: compiler inserts lgkmcnt wait
      size_t gvbase = ((size_t)h * 65536 + n0 + l) * 64;
#pragma unroll
      for (int i = 0; i < 8; ++i) {
        int byte = (l * 128 + i * 16) ^ ((l & 7) << 4);
        us8 o = *reinterpret_cast<const us8*>(scr + byte);
        *reinterpret_cast<us8*>(&vglob[gvbase + i * 8]) = o;
      }
    } else {
      // dd tiles: j==6 -> phi_q, j==7 -> phi_k; wave handles 2 heads
      bool isq = (j == 6);
      unsigned short* dst = isq ? phiq : phik;
      const float* dgrow = diag_s[isq ? 0 : 1];
#pragma unroll
      for (int hp = 0; hp < 2; ++hp) {
        int h = (tl - (isq ? 24 : 28)) * 2 + hp;
        char* st = scr + hp * 4096;   // 2KB-row halves (4KB each)
#pragma unroll
        for (int fj2 = 0; fj2 < 2; ++fj2) {
          int m = fj2 * 16 + li;
          bool valid = (m < 30);
#pragma unroll
          for (int fi = 0; fi < 4; ++fi)
#pragma unroll
            for (int r = 0; r < 4; ++r) {
              int tok = fi * 16 + g * 4 + r;
              float ph = valid
                  ? (RATIO * __expf(acc[fi][hp * 2 + fj2][r] - dgrow[h * 64 + tok]) + REPS)
                  : 0.0f;
              int byte = (tok * 64 + m * 2) ^ ((tok & 7) << 4);
              *reinterpret_cast<unsigned short*>(st + byte) = f2b(ph);
            }
        }
        size_t gbase = ((size_t)h * 65536 + n0 + l) * 32;
#pragma unroll
        for (int i = 0; i < 4; ++i) {
          int byte = (l * 64 + i * 16) ^ ((l & 7) << 4);
          us8 o = *reinterpret_cast<const us8*>(st + byte);
          *reinterpret_cast<us8*>(&dst[gbase + i * 8]) = o;
        }
      }
    }
  }
}

// ---------------- K2: kvs += phi_k^T @ v, ksum += sum phi_k ----------------
__global__ __launch_bounds__(256) void k_kvs(
    const unsigned short* __restrict__ phik, const unsigned short* __restrict__ vglob,
    float* __restrict__ kvs, float* __restrict__ ksum) {
  __shared__ unsigned short phit[32 * 64];  // [m][tok] bf16, swizzled
  __shared__ unsigned short vts[64 * 64];   // [d][tok] bf16, swizzled
  __shared__ float ksums[32];

  int tid = threadIdx.x;
  int w = tid >> 6, l = tid & 63, g = l >> 4, li = l & 15;
  int bid = blockIdx.x;
  int bh = bid >> 2, chunk = bid & 3;
  int b = bh >> 3, h = bh & 7;
  if (tid < 32) ksums[tid] = 0.f;

  int ptok = tid & 63;
  int mseg = tid >> 6;
  float kpart[8] = {0, 0, 0, 0, 0, 0, 0, 0};
  f32x4 acc[2] = {};
  int tok0 = chunk * 1024;

  for (int tile = 0; tile < 16; ++tile) {
    int t0 = tok0 + tile * 64;
    __syncthreads();
    {
      int n = b * 4096 + t0 + ptok;
      us8 p8 = *reinterpret_cast<const us8*>(&phik[((size_t)h * 65536 + n) * 32 + mseg * 8]);
#pragma unroll
      for (int j = 0; j < 8; ++j) {
        int m = mseg * 8 + j;
        kpart[j] += b2f(p8[j]);
        int byte = (m * 128 + ptok * 2) ^ ((m & 7) << 4);
        *reinterpret_cast<unsigned short*>(((char*)phit) + byte) = p8[j];
      }
    }
    {
      int tok2 = tid >> 2, cs = tid & 3;
      const unsigned short* src = vglob + ((size_t)h * 65536 + b * 4096 + t0 + tok2) * 64 + cs * 16;
      us8 v0 = *reinterpret_cast<const us8*>(src);
      us8 v1 = *reinterpret_cast<const us8*>(src + 8);
#pragma unroll
      for (int e = 0; e < 8; ++e) {
        int d0 = cs * 16 + e, d1 = cs * 16 + 8 + e;
        int byte0 = (d0 * 128 + tok2 * 2) ^ ((d0 & 7) << 4);
        int byte1 = (d1 * 128 + tok2 * 2) ^ ((d1 & 7) << 4);
        *reinterpret_cast<unsigned short*>(((char*)vts) + byte0) = v0[e];
        *reinterpret_cast<unsigned short*>(((char*)vts) + byte1) = v1[e];
      }
    }
    __syncthreads();
#pragma unroll
    for (int ks = 0; ks < 2; ++ks) {
      int byteA0 = (li * 128 + (ks * 32 + g * 8) * 2) ^ ((li & 7) << 4);
      int byteA1 = ((16 + li) * 128 + (ks * 32 + g * 8) * 2) ^ ((li & 7) << 4);
      int dcol = w * 16 + li;
      int byteB = (dcol * 128 + (ks * 32 + g * 8) * 2) ^ ((dcol & 7) << 4);
      short8 a0 = *reinterpret_cast<const short8*>(((const char*)phit) + byteA0);
      short8 a1 = *reinterpret_cast<const short8*>(((const char*)phit) + byteA1);
      short8 bb = *reinterpret_cast<const short8*>(((const char*)vts) + byteB);
      acc[0] = __builtin_amdgcn_mfma_f32_16x16x32_bf16(a0, bb, acc[0], 0, 0, 0);
      acc[1] = __builtin_amdgcn_mfma_f32_16x16x32_bf16(a1, bb, acc[1], 0, 0, 0);
    }
  }
#pragma unroll
  for (int fm = 0; fm < 2; ++fm)
#pragma unroll
    for (int r = 0; r < 4; ++r) {
      int m = fm * 16 + g * 4 + r;
      int d = w * 16 + li;
      atomicAdd(&kvs[(size_t)bh * 2048 + m * 64 + d], acc[fm][r]);
    }
#pragma unroll
  for (int j = 0; j < 8; ++j) atomicAdd(&ksums[mseg * 8 + j], kpart[j]);
  __syncthreads();
  if (tid < 32) atomicAdd(&ksum[bh * 32 + tid], ksums[tid]);
}

// ---------------- K3: fold Wo into kvs: Gt[bh][c][m] ----------------
__global__ __launch_bounds__(256) void k_fold(
    const float* __restrict__ kvs, const float* __restrict__ wo,
    unsigned short* __restrict__ Gt) {
  __shared__ float kv[32 * 64];
  __shared__ float wos[64 * 64];  // [d][c]
  int tid = threadIdx.x;
  int bh = blockIdx.x, h = bh & 7;
  for (int i = tid; i < 2048; i += 256) kv[i] = kvs[(size_t)bh * 2048 + i];
  {
    int c = tid >> 2, dseg = tid & 3;
#pragma unroll
    for (int jj = 0; jj < 16; ++jj) {
      int d = dseg * 16 + jj;
      wos[d * 64 + c] = wo[c * 512 + h * 64 + d];
    }
  }
  __syncthreads();
  int c = tid & 63, mseg = tid >> 6;
  us8 outv;
#pragma unroll
  for (int jj = 0; jj < 8; ++jj) {
    int m = mseg * 8 + jj;
    float a = 0.f;
    for (int d = 0; d < 64; ++d) a += kv[m * 64 + d] * wos[d * 64 + c];
    outv[jj] = f2b(a);
  }
  *reinterpret_cast<us8*>(Gt + ((size_t)bh * 64 + c) * 32 + mseg * 8) = outv;
}

// ---------------- K4: out = sum_h (phi_q @ G_h^T)/den_h + bias (f32 out) ----------------
__global__ __launch_bounds__(256) void k_out(
    const unsigned short* __restrict__ phiq, const unsigned short* __restrict__ Gt,
    const float* __restrict__ ksum, const float* __restrict__ wob,
    float* __restrict__ out) {
  int tid = threadIdx.x;
  int w = tid >> 6, l = tid & 63, g = l >> 4, li = l & 15;
  int n0 = blockIdx.x * 64 + w * 16;
  int b = (blockIdx.x * 64) >> 12;
  const short* phi_s = reinterpret_cast<const short*>(phiq);
  const short* gt_s = reinterpret_cast<const short*>(Gt);
  f32x4 oacc[4] = {};
#pragma unroll
  for (int h = 0; h < 8; ++h) {
    int bh = b * 8 + h;
    int tok = n0 + li;
    short8 a = *reinterpret_cast<const short8*>(phi_s + ((size_t)h * 65536 + tok) * 32 + g * 8);
    const float* ksrow = ksum + bh * 32 + g * 8;
    float den = 0.f;
#pragma unroll
    for (int jj = 0; jj < 8; ++jj) den += b2f((unsigned short)a[jj]) * ksrow[jj];
    den += __shfl_xor(den, 16, 64);
    den += __shfl_xor(den, 32, 64);
    float rd = 1.0f / den;
    f32x4 nm[4];
#pragma unroll
    for (int fj = 0; fj < 4; ++fj) {
      short8 bb = *reinterpret_cast<const short8*>(gt_s + ((size_t)bh * 64 + fj * 16 + li) * 32 + g * 8);
      f32x4 z = {};
      nm[fj] = __builtin_amdgcn_mfma_f32_16x16x32_bf16(a, bb, z, 0, 0, 0);
    }
#pragma unroll
    for (int r = 0; r < 4; ++r) {
      float rdr = __shfl(rd, g * 4 + r, 64);
#pragma unroll
      for (int fj = 0; fj < 4; ++fj) oacc[fj][r] += nm[fj][r] * rdr;
    }
  }
#pragma unroll
  for (int fj = 0; fj < 4; ++fj) {
    float bias = wob[fj * 16 + li];
#pragma unroll
    for (int r = 0; r < 4; ++r) {
      int n = n0 + g * 4 + r;
      out[(size_t)n * 64 + fj * 16 + li] = oacc[fj][r] + bias;
    }
  }
}

extern "C" void kernel_launch(void* const* d_in, const int* in_sizes, int n_in,
                              void* d_out, int out_size, void* d_ws, size_t ws_size,
                              hipStream_t stream) {
  const int expect[10] = {8388608, 65536, 512, 65536, 512, 65536, 512, 32768, 64, 1920};
  if (n_in != 10) return;
  for (int i = 0; i < 10; ++i) if (in_sizes[i] != expect[i]) return;
  if (out_size != 4194304) return;
  if (ws_size < WS_NEED) return;

  const float* x    = (const float*)d_in[0];
  const float* wq   = (const float*)d_in[1];
  const float* bq   = (const float*)d_in[2];
  const float* wk   = (const float*)d_in[3];
  const float* bk   = (const float*)d_in[4];
  const float* wv   = (const float*)d_in[5];
  const float* bv   = (const float*)d_in[6];
  const float* wo   = (const float*)d_in[7];
  const float* wob  = (const float*)d_in[8];
  const float* proj = (const float*)d_in[9];

  char* ws = (char*)d_ws;
  unsigned short* wqkv = (unsigned short*)(ws + OF_WQKV);
  float*          wbp  = (float*)(ws + OF_WBP);
  unsigned short* phiq = (unsigned short*)(ws + OF_PHIQ);
  unsigned short* phik = (unsigned short*)(ws + OF_PHIK);
  unsigned short* vgl  = (unsigned short*)(ws + OF_V);
  float*          kvs  = (float*)(ws + OF_KVS);
  float*          ksum = (float*)(ws + OF_KSUM);
  unsigned short* Gt   = (unsigned short*)(ws + OF_GT);

  (void)hipMemsetAsync(ws + OF_KVS, 0, 1048576 + 16384, stream);

  k_pack<<<785, 256, 0, stream>>>(wq, wk, wv, bq, bk, bv, proj, wqkv, wbp);
  k_qkv<<<1024, 256, 0, stream>>>(x, wqkv, wbp, phiq, phik, vgl);
  k_kvs<<<512, 256, 0, stream>>>(phik, vgl, kvs, ksum);
  k_fold<<<128, 256, 0, stream>>>(kvs, wo, Gt);
  k_out<<<1024, 256, 0, stream>>>(phiq, Gt, ksum, wob, (float*)d_out);
}